// Round 9
// baseline (231.651 us; speedup 1.0000x reference)
//
#include <hip/hip_runtime.h>
#include <hip/hip_bf16.h>

// Problem constants
#define BB 2
#define SS 2048
#define DD 1024
#define HH 16
#define HD 64
#define NREL 129
#define LOG2E 1.4426950408889634f
#define SCALEQ (LOG2E / 8.0f)   // folded into Q at projection time
#define KVB 131072l              // elems per bh in ktile/vtile (32*8*64*8)

typedef short s8v __attribute__((ext_vector_type(8)));
typedef short s4v __attribute__((ext_vector_type(4)));
typedef float f4 __attribute__((ext_vector_type(4)));
typedef unsigned int u32x2 __attribute__((ext_vector_type(2)));

#define MFMA_BF16 __builtin_amdgcn_mfma_f32_16x16x32_bf16

__device__ __forceinline__ float bf2f(unsigned short u) {
  union { unsigned int i; float f; } x; x.i = ((unsigned int)u) << 16; return x.f;
}
__device__ __forceinline__ unsigned short f2bf(float f) {
  union { float f; unsigned int i; } x; x.f = f;
  unsigned int r = x.i + 0x7fffu + ((x.i >> 16) & 1u);
  return (unsigned short)(r >> 16);
}
__device__ __forceinline__ unsigned int pk2bf(float a, float b) {
  union { __hip_bfloat162 h2; unsigned int u; } c;
  c.h2 = __float22bfloat162_rn(float2{a, b});
  return c.u;
}
// async global->LDS DMA, 16B/lane; global src MUST be lane-contiguous for
// coalescing (tiled layouts below guarantee it); LDS dest = base + lane*16
__device__ __forceinline__ void gl_lds16(const void* g, void* l) {
  __builtin_amdgcn_global_load_lds(
      (const __attribute__((address_space(1))) unsigned int*)g,
      (__attribute__((address_space(3))) unsigned int*)l, 16, 0, 0);
}

// ---- gfx950 16-lane-row swaps (P transpose, in-register) ------------------
// permlane32_swap(a,b): a'=[a0,a1,b0,b1], b'=[a2,a3,b2,b3]  (rows = 16 lanes)
// permlane16_swap(a,b): a'=[a0,b0,a2,b2], b'=[a1,b1,a3,b3]
// Operands must be distinct values (verified working in round 8).
__device__ __forceinline__ u32x2 pl32(unsigned a, unsigned b) {
  return __builtin_amdgcn_permlane32_swap(a, b, false, false);
}
__device__ __forceinline__ u32x2 pl16(unsigned a, unsigned b) {
  return __builtin_amdgcn_permlane16_swap(a, b, false, false);
}
// Build the PV B-operand fragment from 8 per-lane P values (round-8-proven).
__device__ __forceinline__ s8v mkfrag(float p0, float p1, float p2, float p3,
                                      float p4, float p5, float p6, float p7) {
  u32x2 sa = pl32(pk2bf(p0, p1), pk2bf(p4, p5));
  u32x2 ta = pl16(sa[0], sa[1]);
  u32x2 sb = pl32(pk2bf(p2, p3), pk2bf(p6, p7));
  u32x2 tb = pl16(sb[0], sb[1]);
  unsigned fr[4] = {ta[0], tb[0], ta[1], tb[1]};
  return *(s8v*)fr;
}

// ---------------------------------------------------------------------------
// Fused conversion kernel. grid (2048, 4):
//  y in {0,1,2}: fp32->bf16 convert of input y into Xb (+mask pre-scale).
//  y == 3, x < 768: weight transpose+convert into WTt tiled layout.
__global__ __launch_bounds__(256) void cvt_fused(
    const float* __restrict__ xq, const float* __restrict__ xk,
    const float* __restrict__ xv, const float* __restrict__ mask,
    const float* __restrict__ Wq, const float* __restrict__ Wk,
    const float* __restrict__ Wv,
    unsigned short* __restrict__ xb, float* __restrict__ mkg,
    unsigned short* __restrict__ WTt) {
  __shared__ unsigned short tile[64][72];
  const int y = blockIdx.y;
  const int t = threadIdx.x;
  if (y < 3) {
    const float* in = (y == 0) ? xq : (y == 1) ? xk : xv;
    unsigned short* out = xb + (long)y * 4096 * DD;
    const long i = ((long)blockIdx.x * 256 + t) * 8;
    f4 a = *(const f4*)(in + i);
    f4 b = *(const f4*)(in + i + 4);
    unsigned int u[4];
    u[0] = pk2bf(a[0], a[1]); u[1] = pk2bf(a[2], a[3]);
    u[2] = pk2bf(b[0], b[1]); u[3] = pk2bf(b[2], b[3]);
    *(s8v*)(out + i) = *(s8v*)u;
    if (y == 0 && blockIdx.x < BB) {
      const int row = blockIdx.x;
      const long j = (long)row * SS + t * 8;
      f4 ma = *(const f4*)(mask + j);
      f4 mb = *(const f4*)(mask + j + 4);
      #pragma unroll
      for (int e = 0; e < 4; ++e) {
        mkg[j + e] = ma[e] * LOG2E;
        mkg[j + 4 + e] = mb[e] * LOG2E;
      }
    }
    return;
  }
  // weight path: decode 768 blocks -> (cx, cy, cz)
  const int bx = blockIdx.x;
  if (bx >= 768) return;
  const int cz = bx >> 8, rem = bx & 255, cx = rem & 15, cy = rem >> 4;
  const float* in = (cz == 0) ? Wq : (cz == 1) ? Wk : Wv;
  unsigned short* out = WTt + (long)cz * 1048576;
  const int c0 = cx * 64, r0 = cy * 64;  // c0: n-base, r0: k-base
  const int r = t >> 2;
  #pragma unroll
  for (int j = 0; j < 4; ++j) {
    int cc = (t & 3) * 16 + j * 4;
    f4 v = *(const f4*)(in + (long)(r0 + r) * DD + c0 + cc);
    #pragma unroll
    for (int e = 0; e < 4; ++e) tile[r][cc + e] = f2bf(v[e]);
  }
  __syncthreads();
  const int c = t >> 2;           // n within 64-tile
  #pragma unroll
  for (int h = 0; h < 2; ++h) {
    int r8 = (t & 3) + 4 * h;     // k-octet within 64-tile
    unsigned short vals[8];
    #pragma unroll
    for (int j = 0; j < 8; ++j) vals[j] = tile[r8 * 8 + j][c];
    int n = c0 + c, kb = r0 + r8 * 8;
    long off = ((long)(n >> 7) * 131072) + ((kb >> 6) * 8192) +
               (((kb & 63) >> 3) * 1024) + ((n & 127) * 8);
    *(s8v*)(out + off) = *(s8v*)vals;
  }
}

// ---------------------------------------------------------------------------
// Fused QKV projection GEMM: C = Xb @ W + bias.
// NEW: double-buffered wt (2x16KB) + double-buffered A fragments; staging for
// step i+1 issues right after the barrier and hides under step i's 32 MFMAs;
// ONE barrier per k-step (was 2, with fully exposed staging latency).
// Race safety: barrier at end of step i means (a) every wave's DMA for step
// i+1's buffer landed (own vmcnt(0) precedes barrier) and (b) every wave is
// done reading the buffer that step i+1's prefetch will overwrite.
// launch_bounds(256,2): natural VGPR (~150), no forced spill.
// grid (8 n, 32 m, 3 z), block 256.
__global__ __launch_bounds__(256, 2) void proj_gemm(
    const unsigned short* __restrict__ Xb, const unsigned short* __restrict__ WTt,
    const float* __restrict__ bq, const float* __restrict__ bk,
    const float* __restrict__ bv,
    unsigned short* __restrict__ qbuf, unsigned short* __restrict__ ktile,
    unsigned short* __restrict__ vtile) {
  __shared__ __align__(16) unsigned short wt[2][8][128][8];  // [buf][kc][n][8k] 32KB
  const int z = blockIdx.z;
  const unsigned short* X = Xb + (long)z * 4096 * DD;
  const unsigned short* WTz = WTt + (long)z * 1048576;
  const float* bias = (z == 0) ? bq : (z == 1) ? bk : bv;

  const int n0 = blockIdx.x * 128, m0 = blockIdx.y * 128;
  const int t = threadIdx.x, w = t >> 6, l = t & 63;
  const int lm = l & 15, qd = l >> 4;

  f4 acc[8][2];
  #pragma unroll
  for (int i = 0; i < 8; ++i) { acc[i][0] = (f4)0.0f; acc[i][1] = (f4)0.0f; }

  const unsigned short* x0 = X + (long)(m0 + w * 32 + lm) * DD;
  const unsigned short* x1 = x0 + 16 * DD;
  const unsigned short* wtile0 = WTz + (long)(n0 >> 7) * 131072;

#define STAGE_WT(STEP, BUF) do {                                          \
    const unsigned short* tb_ = wtile0 + (STEP) * 8192;                   \
    _Pragma("unroll")                                                     \
    for (int i_ = 0; i_ < 4; ++i_) {                                      \
      int idx_ = w * 4 + i_;                                              \
      gl_lds16(tb_ + idx_ * 512 + l * 8, &wt[BUF][0][0][0] + idx_ * 512); \
    }                                                                     \
  } while (0)
#define LOAD_A(STEP, A) do {                                              \
    int k0_ = (STEP) * 64;                                                \
    A[0] = *(const s8v*)(x0 + k0_ + qd * 8);                              \
    A[1] = *(const s8v*)(x0 + k0_ + 32 + qd * 8);                         \
    A[2] = *(const s8v*)(x1 + k0_ + qd * 8);                              \
    A[3] = *(const s8v*)(x1 + k0_ + 32 + qd * 8);                         \
  } while (0)
#define MFMA_STEP(BUF, A) do {                                            \
    _Pragma("unroll")                                                     \
    for (int cb_ = 0; cb_ < 8; ++cb_) {                                   \
      s8v b0_ = *(const s8v*)&wt[BUF][qd][cb_ * 16 + lm][0];              \
      s8v b1_ = *(const s8v*)&wt[BUF][4 + qd][cb_ * 16 + lm][0];          \
      acc[cb_][0] = MFMA_BF16(A[0], b0_, acc[cb_][0], 0, 0, 0);           \
      acc[cb_][0] = MFMA_BF16(A[1], b1_, acc[cb_][0], 0, 0, 0);           \
      acc[cb_][1] = MFMA_BF16(A[2], b0_, acc[cb_][1], 0, 0, 0);           \
      acc[cb_][1] = MFMA_BF16(A[3], b1_, acc[cb_][1], 0, 0, 0);           \
    }                                                                     \
  } while (0)

  s8v aA[4], aB[4];
  STAGE_WT(0, 0);
  LOAD_A(0, aA);
  asm volatile("s_waitcnt vmcnt(0)" ::: "memory");
  __syncthreads();

  #pragma unroll
  for (int i = 0; i < 16; i += 2) {
    // even step i: compute from buf0/aA, prefetch step i+1 into buf1/aB
    if (i + 1 < 16) { STAGE_WT(i + 1, 1); LOAD_A(i + 1, aB); }
    MFMA_STEP(0, aA);
    asm volatile("s_waitcnt vmcnt(0)" ::: "memory");
    __syncthreads();
    // odd step i+1: compute from buf1/aB, prefetch step i+2 into buf0/aA
    if (i + 1 < 16) {
      if (i + 2 < 16) { STAGE_WT(i + 2, 0); LOAD_A(i + 2, aA); }
      MFMA_STEP(1, aB);
      asm volatile("s_waitcnt vmcnt(0)" ::: "memory");
      __syncthreads();
    }
  }
#undef STAGE_WT
#undef LOAD_A
#undef MFMA_STEP

  if (z == 0) {
    // Q: head-split [bh][s][d], pre-scaled
    #pragma unroll
    for (int cb = 0; cb < 8; ++cb) {
      int n = n0 + cb * 16 + lm;
      float bvv = bias[n];
      int hh = n >> 6, d = n & 63;
      #pragma unroll
      for (int ms = 0; ms < 2; ++ms) {
        #pragma unroll
        for (int r = 0; r < 4; ++r) {
          int m = m0 + w * 32 + ms * 16 + qd * 4 + r;
          int bidx = m >> 11, s = m & (SS - 1);
          qbuf[((long)(bidx * HH + hh) * SS + s) * HD + d] =
              f2bf((acc[cb][ms][r] + bvv) * SCALEQ);
        }
      }
    }
  } else if (z == 1) {
    // K -> ktile[bh][g][c][key][8]
    #pragma unroll
    for (int cb = 0; cb < 8; ++cb) {
      int n = n0 + cb * 16 + lm;
      float bvv = bias[n];
      int hh = n >> 6, d = n & 63;
      int c = d >> 3, e = d & 7;
      #pragma unroll
      for (int ms = 0; ms < 2; ++ms) {
        #pragma unroll
        for (int r = 0; r < 4; ++r) {
          int m = m0 + w * 32 + ms * 16 + qd * 4 + r;
          int bidx = m >> 11, s = m & (SS - 1);
          long bh = bidx * HH + hh;
          ktile[bh * KVB + (s >> 6) * 4096 + c * 512 + (s & 63) * 8 + e] =
              f2bf(acc[cb][ms][r] + bvv);
        }
      }
    }
  } else {
    // V -> vtile[bh][g][c][d][8], 4 consecutive s per 8B store
    #pragma unroll
    for (int cb = 0; cb < 8; ++cb) {
      int n = n0 + cb * 16 + lm;
      float bvv = bias[n];
      int hh = n >> 6, d = n & 63;
      #pragma unroll
      for (int ms = 0; ms < 2; ++ms) {
        int m = m0 + w * 32 + ms * 16 + qd * 4;
        int bidx = m >> 11, s = m & (SS - 1);
        long bh = bidx * HH + hh;
        unsigned short o4[4];
        #pragma unroll
        for (int r = 0; r < 4; ++r) o4[r] = f2bf(acc[cb][ms][r] + bvv);
        *(s4v*)&vtile[bh * KVB + (s >> 6) * 4096 + ((s & 63) >> 3) * 512 +
                      d * 8 + (s & 7)] = *(s4v*)o4;
      }
    }
  }
}

// ---------------------------------------------------------------------------
// Flash attention — UNCHANGED from round 8 (86 µs, passed, conflicts 0.98M).
__global__ __launch_bounds__(256, 2) void attn(
    const unsigned short* __restrict__ qb, const unsigned short* __restrict__ ktile,
    const unsigned short* __restrict__ vtile, const float* __restrict__ tableF,
    const float* __restrict__ mkg, float* __restrict__ out) {
  __shared__ __align__(16) unsigned short ks[2][8][64][8];  // [buf][d-chunk][key][8d]
  __shared__ __align__(16) unsigned short vs[2][8][64][8];  // [buf][k-chunk][d][8k]
  __shared__ __align__(16) unsigned short qr2[NREL][130];   // [dist][q_local+pad]

  const int bh = blockIdx.y, b = bh >> 4, h = bh & 15;
  const int q0 = blockIdx.x * 128;
  const int t = threadIdx.x, w = t >> 6, l = t & 63;
  const int lm = l & 15, qd = l >> 4;
  const int qw = q0 + w * 32;          // this wave's q base (32 rows)
  const int qc0 = w * 32 + lm, qc1 = qc0 + 16;  // local q cols of the 2 subtiles

  const unsigned short* kkb = ktile + (long)bh * KVB;
  const unsigned short* vvb = vtile + (long)bh * KVB;

  // stage round 0 (key-group 0) into buf 0: lane-contiguous 1KB bursts
  #pragma unroll
  for (int i = 0; i < 2; ++i) {
    int c = 2 * w + i;
    gl_lds16(kkb + c * 512 + l * 8, &ks[0][c][0][0]);
    gl_lds16(vvb + c * 512 + l * 8, &vs[0][c][0][0]);
  }

  // Q fragments for both subtiles (q = qw + lm and qw + 16 + lm), pre-scaled
  const unsigned short* qrow = qb + ((long)bh * SS + qw + lm) * HD;
  const s8v qa0 = *(const s8v*)(qrow + qd * 8);
  const s8v qa1 = *(const s8v*)(qrow + 32 + qd * 8);
  const s8v qb0 = *(const s8v*)(qrow + 16 * HD + qd * 8);
  const s8v qb1 = *(const s8v*)(qrow + 16 * HD + 32 + qd * 8);

  // Fused qrel: qr2[dist][q_local] = q_scaled . table[dist], both subtiles
  #pragma unroll
  for (int cb = 0; cb < 9; ++cb) {
    int dist = cb * 16 + lm;
    int dc = dist > NREL - 1 ? NREL - 1 : dist;
    const float* trow = tableF + dc * HD;
    f4 t0 = *(const f4*)(trow + qd * 8);
    f4 t1 = *(const f4*)(trow + qd * 8 + 4);
    f4 t2 = *(const f4*)(trow + 32 + qd * 8);
    f4 t3 = *(const f4*)(trow + 32 + qd * 8 + 4);
    unsigned int tb[8];
    tb[0] = pk2bf(t0[0], t0[1]); tb[1] = pk2bf(t0[2], t0[3]);
    tb[2] = pk2bf(t1[0], t1[1]); tb[3] = pk2bf(t1[2], t1[3]);
    tb[4] = pk2bf(t2[0], t2[1]); tb[5] = pk2bf(t2[2], t2[3]);
    tb[6] = pk2bf(t3[0], t3[1]); tb[7] = pk2bf(t3[2], t3[3]);
    s8v b0 = *(s8v*)tb, b1 = *(s8v*)(tb + 4);
    f4 c0 = MFMA_BF16(qa0, b0, (f4)0.0f, 0, 0, 0);
    c0 = MFMA_BF16(qa1, b1, c0, 0, 0, 0);
    f4 c1 = MFMA_BF16(qb0, b0, (f4)0.0f, 0, 0, 0);
    c1 = MFMA_BF16(qb1, b1, c1, 0, 0, 0);
    if (dist <= NREL - 1) {
      #pragma unroll
      for (int r = 0; r < 4; ++r) {
        qr2[dist][w * 32 + qd * 4 + r] = f2bf(c0[r]);
        qr2[dist][w * 32 + 16 + qd * 4 + r] = f2bf(c1[r]);
      }
    }
  }
  asm volatile("s_waitcnt vmcnt(0)" ::: "memory");
  __syncthreads();

  const float bLo0 = bf2f(qr2[0][qc0]), bHi0 = bf2f(qr2[128][qc0]);
  const float bLo1 = bf2f(qr2[0][qc1]), bHi1 = bf2f(qr2[128][qc1]);
  const float* mrow = mkg + b * SS;               // mask*LOG2E (L1-resident)

  float m0_ = -1e30f, l0_ = 0.0f, m1_ = -1e30f, l1_ = 0.0f;
  f4 c40[4], c41[4];
  #pragma unroll
  for (int i = 0; i < 4; ++i) { c40[i] = (f4)0.0f; c41[i] = (f4)0.0f; }

  for (int rr = 0; rr < 32; ++rr) {
    const int kk = rr << 6;
    const int buf = rr & 1;
    if (rr < 31) {
      const int nb = buf ^ 1;
      const unsigned short* kg = kkb + (rr + 1) * 4096;
      const unsigned short* vg = vvb + (rr + 1) * 4096;
      #pragma unroll
      for (int i = 0; i < 2; ++i) {
        int c = 2 * w + i;
        gl_lds16(kg + c * 512 + l * 8, &ks[nb][c][0][0]);
        gl_lds16(vg + c * 512 + l * 8, &vs[nb][c][0][0]);
      }
    }
    // QK^T for both subtiles: K fragments read once, used twice
    f4 st0[4], st1[4];
    #pragma unroll
    for (int tt = 0; tt < 4; ++tt) {
      s8v k0v = *(const s8v*)&ks[buf][qd][tt * 16 + lm][0];
      s8v k1v = *(const s8v*)&ks[buf][4 + qd][tt * 16 + lm][0];
      st0[tt] = MFMA_BF16(k0v, qa0, (f4)0.0f, 0, 0, 0);
      st0[tt] = MFMA_BF16(k1v, qa1, st0[tt], 0, 0, 0);
      st1[tt] = MFMA_BF16(k0v, qb0, (f4)0.0f, 0, 0, 0);
      st1[tt] = MFMA_BF16(k1v, qb1, st1[tt], 0, 0, 0);
    }
    float z0[16], z1[16];
    const int kw = kk - qw;  // key-band offset relative to this wave's q range
    if (kw >= 96) {          // all dist >= 65 for this wave's 32 q
      #pragma unroll
      for (int tt = 0; tt < 4; ++tt) {
        f4 mv = *(const f4*)&mrow[kk + tt * 16 + qd * 4];
        #pragma unroll
        for (int r = 0; r < 4; ++r) {
          z0[tt * 4 + r] = st0[tt][r] + bHi0 + mv[r];
          z1[tt * 4 + r] = st1[tt][r] + bHi1 + mv[r];
        }
      }
    } else if (kw <= -128) { // all dist <= -65
      #pragma unroll
      for (int tt = 0; tt < 4; ++tt) {
        f4 mv = *(const f4*)&mrow[kk + tt * 16 + qd * 4];
        #pragma unroll
        for (int r = 0; r < 4; ++r) {
          z0[tt * 4 + r] = st0[tt][r] + bLo0 + mv[r];
          z1[tt * 4 + r] = st1[tt][r] + bLo1 + mv[r];
        }
      }
    } else {                 // diagonal band (3 iters/wave): LDS qrel lookups
      const int db0 = kw - lm + 64 + qd * 4;
      #pragma unroll
      for (int tt = 0; tt < 4; ++tt) {
        f4 mv = *(const f4*)&mrow[kk + tt * 16 + qd * 4];
        #pragma unroll
        for (int r = 0; r < 4; ++r) {
          int du = db0 + tt * 16 + r;
          int d0 = du < 0 ? 0 : (du > 128 ? 128 : du);
          int d1 = du - 16; d1 = d1 < 0 ? 0 : (d1 > 128 ? 128 : d1);
          z0[tt * 4 + r] = st0[tt][r] + bf2f(qr2[d0][qc0]) + mv[r];
          z1[tt * 4 + r] = st1[tt][r] + bf2f(qr2[d1][qc1]) + mv[r];
        }
      }
    }
    // defer-max with per-group tm; cross-group shuffles only on rescale
    float tm0 = z0[0], tm1 = z1[0];
    #pragma unroll
    for (int i = 1; i < 16; ++i) {
      tm0 = fmaxf(tm0, z0[i]);
      tm1 = fmaxf(tm1, z1[i]);
    }
    if (!__all(tm0 - m0_ <= 8.0f)) {
      tm0 = fmaxf(tm0, __shfl_xor(tm0, 16));
      tm0 = fmaxf(tm0, __shfl_xor(tm0, 32));
      float mn0 = fmaxf(m0_, tm0);
      float al0 = __builtin_amdgcn_exp2f(m0_ - mn0);
      m0_ = mn0; l0_ *= al0;
      #pragma unroll
      for (int db = 0; db < 4; ++db)
        #pragma unroll
        for (int r = 0; r < 4; ++r) c40[db][r] *= al0;
    }
    if (!__all(tm1 - m1_ <= 8.0f)) {
      tm1 = fmaxf(tm1, __shfl_xor(tm1, 16));
      tm1 = fmaxf(tm1, __shfl_xor(tm1, 32));
      float mn1 = fmaxf(m1_, tm1);
      float al1 = __builtin_amdgcn_exp2f(m1_ - mn1);
      m1_ = mn1; l1_ *= al1;
      #pragma unroll
      for (int db = 0; db < 4; ++db)
        #pragma unroll
        for (int r = 0; r < 4; ++r) c41[db][r] *= al1;
    }
    float s0 = 0.0f, s1 = 0.0f;
    #pragma unroll
    for (int i = 0; i < 16; ++i) {
      z0[i] = __builtin_amdgcn_exp2f(z0[i] - m0_); s0 += z0[i];
      z1[i] = __builtin_amdgcn_exp2f(z1[i] - m1_); s1 += z1[i];
    }
    s0 += __shfl_xor(s0, 16);
    s0 += __shfl_xor(s0, 32);
    s1 += __shfl_xor(s1, 16);
    s1 += __shfl_xor(s1, 32);
    l0_ += s0; l1_ += s1;

    // PV phase A (keys 0..31): P fragments built fully in-register
    {
      s8v pa0 = mkfrag(z0[0], z0[1], z0[2], z0[3], z0[4], z0[5], z0[6], z0[7]);
      s8v pa1 = mkfrag(z1[0], z1[1], z1[2], z1[3], z1[4], z1[5], z1[6], z1[7]);
      #pragma unroll
      for (int db = 0; db < 4; ++db) {
        s8v va = *(const s8v*)&vs[buf][qd][db * 16 + lm][0];
        c40[db] = MFMA_BF16(va, pa0, c40[db], 0, 0, 0);
        c41[db] = MFMA_BF16(va, pa1, c41[db], 0, 0, 0);
      }
    }
    // PV phase B (keys 32..63)
    {
      s8v pB0 = mkfrag(z0[8], z0[9], z0[10], z0[11], z0[12], z0[13], z0[14], z0[15]);
      s8v pB1 = mkfrag(z1[8], z1[9], z1[10], z1[11], z1[12], z1[13], z1[14], z1[15]);
      #pragma unroll
      for (int db = 0; db < 4; ++db) {
        s8v vb = *(const s8v*)&vs[buf][4 + qd][db * 16 + lm][0];
        c40[db] = MFMA_BF16(vb, pB0, c40[db], 0, 0, 0);
        c41[db] = MFMA_BF16(vb, pB1, c41[db], 0, 0, 0);
      }
    }
    asm volatile("s_waitcnt vmcnt(0)" ::: "memory");
    __syncthreads();
  }

  const float inv0 = 1.0f / l0_, inv1 = 1.0f / l1_;
  float* ob0 = out + ((long)b * SS + q0 + qc0) * DD + h * HD;
  float* ob1 = out + ((long)b * SS + q0 + qc1) * DD + h * HD;
  #pragma unroll
  for (int db = 0; db < 4; ++db) {
    f4 o0, o1;
    #pragma unroll
    for (int r = 0; r < 4; ++r) {
      o0[r] = c40[db][r] * inv0;
      o1[r] = c41[db][r] * inv1;
    }
    *(f4*)(ob0 + db * 16 + qd * 4) = o0;
    *(f4*)(ob1 + db * 16 + qd * 4) = o1;
  }
}

// ---------------------------------------------------------------------------
extern "C" void kernel_launch(void* const* d_in, const int* in_sizes, int n_in,
                              void* d_out, int out_size, void* d_ws, size_t ws_size,
                              hipStream_t stream) {
  const float* query = (const float*)d_in[0];
  const float* key   = (const float*)d_in[1];
  const float* value = (const float*)d_in[2];
  const float* mask  = (const float*)d_in[3];
  const float* Wq    = (const float*)d_in[4];
  const float* bq    = (const float*)d_in[5];
  const float* Wk    = (const float*)d_in[6];
  const float* bk    = (const float*)d_in[7];
  const float* Wv    = (const float*)d_in[8];
  const float* bv    = (const float*)d_in[9];
  const float* table = (const float*)d_in[10];

  char* ws = (char*)d_ws;
  // workspace layout (bytes), span 56 MB
  unsigned short* WTt   = (unsigned short*)(ws);               // 6,291,456 (tiled)
  float*          mkg   = (float*)(ws + (7l << 20));           // 16 KB mask*LOG2E
  unsigned short* Xb    = (unsigned short*)(ws + (8l << 20));  // 25,165,824
  unsigned short* qbuf  = (unsigned short*)(ws + (32l << 20));
  unsigned short* ktile = (unsigned short*)(ws + (40l << 20));
  unsigned short* vtile = (unsigned short*)(ws + (48l << 20));

  // 1) fused conversions: inputs fp32->bf16 + mask pre-scale + weight tiling
  cvt_fused<<<dim3(2048, 4, 1), 256, 0, stream>>>(
      query, key, value, mask, Wq, Wk, Wv, Xb, mkg, WTt);

  // 2) fused QKV projections (double-buffered, 1 barrier/k-step)
  proj_gemm<<<dim3(8, 32, 3), 256, 0, stream>>>(Xb, WTt, bq, bk, bv,
                                                qbuf, ktile, vtile);

  // 3) flash attention (round-8 proven: permlane P-transpose, defer-max)
  attn<<<dim3(16, 32, 1), 256, 0, stream>>>(qbuf, ktile, vtile, table,
                                            mkg, (float*)d_out);
}

// Round 10
// 224.347 us; speedup vs baseline: 1.0326x; 1.0326x over previous
//
#include <hip/hip_runtime.h>
#include <hip/hip_bf16.h>

// Problem constants
#define BB 2
#define SS 2048
#define DD 1024
#define HH 16
#define HD 64
#define NREL 129
#define LOG2E 1.4426950408889634f
#define SCALEQ (LOG2E / 8.0f)   // folded into Q at projection time
#define KVB 131072l              // elems per bh in ktile/vtile (32*8*64*8)

typedef short s8v __attribute__((ext_vector_type(8)));
typedef short s4v __attribute__((ext_vector_type(4)));
typedef float f4 __attribute__((ext_vector_type(4)));
typedef unsigned int u32x2 __attribute__((ext_vector_type(2)));

#define MFMA_BF16 __builtin_amdgcn_mfma_f32_16x16x32_bf16

__device__ __forceinline__ float bf2f(unsigned short u) {
  union { unsigned int i; float f; } x; x.i = ((unsigned int)u) << 16; return x.f;
}
__device__ __forceinline__ unsigned short f2bf(float f) {
  union { float f; unsigned int i; } x; x.f = f;
  unsigned int r = x.i + 0x7fffu + ((x.i >> 16) & 1u);
  return (unsigned short)(r >> 16);
}
__device__ __forceinline__ unsigned int pk2bf(float a, float b) {
  union { __hip_bfloat162 h2; unsigned int u; } c;
  c.h2 = __float22bfloat162_rn(float2{a, b});
  return c.u;
}
// async global->LDS DMA, 16B/lane; global src MUST be lane-contiguous for
// coalescing (tiled layouts below guarantee it); LDS dest = base + lane*16
__device__ __forceinline__ void gl_lds16(const void* g, void* l) {
  __builtin_amdgcn_global_load_lds(
      (const __attribute__((address_space(1))) unsigned int*)g,
      (__attribute__((address_space(3))) unsigned int*)l, 16, 0, 0);
}

// ---- gfx950 16-lane-row swaps (P transpose, in-register) ------------------
// permlane32_swap(a,b): a'=[a0,a1,b0,b1], b'=[a2,a3,b2,b3]  (rows = 16 lanes)
// permlane16_swap(a,b): a'=[a0,b0,a2,b2], b'=[a1,b1,a3,b3]
// Operands must be distinct values (verified working in round 8).
__device__ __forceinline__ u32x2 pl32(unsigned a, unsigned b) {
  return __builtin_amdgcn_permlane32_swap(a, b, false, false);
}
__device__ __forceinline__ u32x2 pl16(unsigned a, unsigned b) {
  return __builtin_amdgcn_permlane16_swap(a, b, false, false);
}
// Build the PV B-operand fragment from 8 per-lane P values (round-8-proven).
__device__ __forceinline__ s8v mkfrag(float p0, float p1, float p2, float p3,
                                      float p4, float p5, float p6, float p7) {
  u32x2 sa = pl32(pk2bf(p0, p1), pk2bf(p4, p5));
  u32x2 ta = pl16(sa[0], sa[1]);
  u32x2 sb = pl32(pk2bf(p2, p3), pk2bf(p6, p7));
  u32x2 tb = pl16(sb[0], sb[1]);
  unsigned fr[4] = {ta[0], tb[0], ta[1], tb[1]};
  return *(s8v*)fr;
}

// ---------------------------------------------------------------------------
// Fused conversion kernel. grid (2048, 4):
//  y in {0,1,2}: fp32->bf16 convert of input y into Xb (+mask pre-scale).
//  y == 3, x < 768: weight transpose+convert into WTt tiled layout.
__global__ __launch_bounds__(256) void cvt_fused(
    const float* __restrict__ xq, const float* __restrict__ xk,
    const float* __restrict__ xv, const float* __restrict__ mask,
    const float* __restrict__ Wq, const float* __restrict__ Wk,
    const float* __restrict__ Wv,
    unsigned short* __restrict__ xb, float* __restrict__ mkg,
    unsigned short* __restrict__ WTt) {
  __shared__ unsigned short tile[64][72];
  const int y = blockIdx.y;
  const int t = threadIdx.x;
  if (y < 3) {
    const float* in = (y == 0) ? xq : (y == 1) ? xk : xv;
    unsigned short* out = xb + (long)y * 4096 * DD;
    const long i = ((long)blockIdx.x * 256 + t) * 8;
    f4 a = *(const f4*)(in + i);
    f4 b = *(const f4*)(in + i + 4);
    unsigned int u[4];
    u[0] = pk2bf(a[0], a[1]); u[1] = pk2bf(a[2], a[3]);
    u[2] = pk2bf(b[0], b[1]); u[3] = pk2bf(b[2], b[3]);
    *(s8v*)(out + i) = *(s8v*)u;
    if (y == 0 && blockIdx.x < BB) {
      const int row = blockIdx.x;
      const long j = (long)row * SS + t * 8;
      f4 ma = *(const f4*)(mask + j);
      f4 mb = *(const f4*)(mask + j + 4);
      #pragma unroll
      for (int e = 0; e < 4; ++e) {
        mkg[j + e] = ma[e] * LOG2E;
        mkg[j + 4 + e] = mb[e] * LOG2E;
      }
    }
    return;
  }
  // weight path: decode 768 blocks -> (cx, cy, cz)
  const int bx = blockIdx.x;
  if (bx >= 768) return;
  const int cz = bx >> 8, rem = bx & 255, cx = rem & 15, cy = rem >> 4;
  const float* in = (cz == 0) ? Wq : (cz == 1) ? Wk : Wv;
  unsigned short* out = WTt + (long)cz * 1048576;
  const int c0 = cx * 64, r0 = cy * 64;  // c0: n-base, r0: k-base
  const int r = t >> 2;
  #pragma unroll
  for (int j = 0; j < 4; ++j) {
    int cc = (t & 3) * 16 + j * 4;
    f4 v = *(const f4*)(in + (long)(r0 + r) * DD + c0 + cc);
    #pragma unroll
    for (int e = 0; e < 4; ++e) tile[r][cc + e] = f2bf(v[e]);
  }
  __syncthreads();
  const int c = t >> 2;           // n within 64-tile
  #pragma unroll
  for (int h = 0; h < 2; ++h) {
    int r8 = (t & 3) + 4 * h;     // k-octet within 64-tile
    unsigned short vals[8];
    #pragma unroll
    for (int j = 0; j < 8; ++j) vals[j] = tile[r8 * 8 + j][c];
    int n = c0 + c, kb = r0 + r8 * 8;
    long off = ((long)(n >> 7) * 131072) + ((kb >> 6) * 8192) +
               (((kb & 63) >> 3) * 1024) + ((n & 127) * 8);
    *(s8v*)(out + off) = *(s8v*)vals;
  }
}

// ---------------------------------------------------------------------------
// Fused QKV projection GEMM: C = Xb @ W + bias.
// NEW (T1, XCD-aware remap): 1-D grid of 768 blocks; HIP round-robins
// linear block id across the 8 XCDs, so id&7 selects the XCD class.
// Decode: x = id&7 -> m-chunk [4x..4x+3]; j = id>>3: m = 4x+(j&3),
// n = (j>>2)&7, z = j>>5 (z outermost). Each XCD then touches only its
// own 1 MB X-slice + 2 MB WT per z (L2-resident, 4 MB/XCD): X is read
// from HBM ONCE (24 MB) instead of 8x192 MB through L3 (the old mapping
// put XCD = n-index, so every XCD streamed the whole X).
// Double-buffered wt + A fragments, 1 barrier/k-step (round-9-proven).
// grid (768), block 256.
__global__ __launch_bounds__(256, 2) void proj_gemm(
    const unsigned short* __restrict__ Xb, const unsigned short* __restrict__ WTt,
    const float* __restrict__ bq, const float* __restrict__ bk,
    const float* __restrict__ bv,
    unsigned short* __restrict__ qbuf, unsigned short* __restrict__ ktile,
    unsigned short* __restrict__ vtile) {
  __shared__ __align__(16) unsigned short wt[2][8][128][8];  // [buf][kc][n][8k] 32KB
  const int gid = blockIdx.x;
  const int xcls = gid & 7;            // XCD class (round-robin by linear id)
  const int j = gid >> 3;              // 0..95
  const int mI = xcls * 4 + (j & 3);   // m-block 0..31 (XCD owns 4 m-blocks)
  const int nI = (j >> 2) & 7;         // n-block 0..7
  const int z  = j >> 5;               // 0..2 (outermost: one z phase at a time)
  const unsigned short* X = Xb + (long)z * 4096 * DD;
  const unsigned short* WTz = WTt + (long)z * 1048576;
  const float* bias = (z == 0) ? bq : (z == 1) ? bk : bv;

  const int n0 = nI * 128, m0 = mI * 128;
  const int t = threadIdx.x, w = t >> 6, l = t & 63;
  const int lm = l & 15, qd = l >> 4;

  f4 acc[8][2];
  #pragma unroll
  for (int i = 0; i < 8; ++i) { acc[i][0] = (f4)0.0f; acc[i][1] = (f4)0.0f; }

  const unsigned short* x0 = X + (long)(m0 + w * 32 + lm) * DD;
  const unsigned short* x1 = x0 + 16 * DD;
  const unsigned short* wtile0 = WTz + (long)(n0 >> 7) * 131072;

#define STAGE_WT(STEP, BUF) do {                                          \
    const unsigned short* tb_ = wtile0 + (STEP) * 8192;                   \
    _Pragma("unroll")                                                     \
    for (int i_ = 0; i_ < 4; ++i_) {                                      \
      int idx_ = w * 4 + i_;                                              \
      gl_lds16(tb_ + idx_ * 512 + l * 8, &wt[BUF][0][0][0] + idx_ * 512); \
    }                                                                     \
  } while (0)
#define LOAD_A(STEP, A) do {                                              \
    int k0_ = (STEP) * 64;                                                \
    A[0] = *(const s8v*)(x0 + k0_ + qd * 8);                              \
    A[1] = *(const s8v*)(x0 + k0_ + 32 + qd * 8);                         \
    A[2] = *(const s8v*)(x1 + k0_ + qd * 8);                              \
    A[3] = *(const s8v*)(x1 + k0_ + 32 + qd * 8);                         \
  } while (0)
#define MFMA_STEP(BUF, A) do {                                            \
    _Pragma("unroll")                                                     \
    for (int cb_ = 0; cb_ < 8; ++cb_) {                                   \
      s8v b0_ = *(const s8v*)&wt[BUF][qd][cb_ * 16 + lm][0];              \
      s8v b1_ = *(const s8v*)&wt[BUF][4 + qd][cb_ * 16 + lm][0];          \
      acc[cb_][0] = MFMA_BF16(A[0], b0_, acc[cb_][0], 0, 0, 0);           \
      acc[cb_][0] = MFMA_BF16(A[1], b1_, acc[cb_][0], 0, 0, 0);           \
      acc[cb_][1] = MFMA_BF16(A[2], b0_, acc[cb_][1], 0, 0, 0);           \
      acc[cb_][1] = MFMA_BF16(A[3], b1_, acc[cb_][1], 0, 0, 0);           \
    }                                                                     \
  } while (0)

  s8v aA[4], aB[4];
  STAGE_WT(0, 0);
  LOAD_A(0, aA);
  asm volatile("s_waitcnt vmcnt(0)" ::: "memory");
  __syncthreads();

  #pragma unroll
  for (int i = 0; i < 16; i += 2) {
    // even step i: compute from buf0/aA, prefetch step i+1 into buf1/aB
    if (i + 1 < 16) { STAGE_WT(i + 1, 1); LOAD_A(i + 1, aB); }
    MFMA_STEP(0, aA);
    asm volatile("s_waitcnt vmcnt(0)" ::: "memory");
    __syncthreads();
    // odd step i+1: compute from buf1/aB, prefetch step i+2 into buf0/aA
    if (i + 1 < 16) {
      if (i + 2 < 16) { STAGE_WT(i + 2, 0); LOAD_A(i + 2, aA); }
      MFMA_STEP(1, aB);
      asm volatile("s_waitcnt vmcnt(0)" ::: "memory");
      __syncthreads();
    }
  }
#undef STAGE_WT
#undef LOAD_A
#undef MFMA_STEP

  if (z == 0) {
    // Q: head-split [bh][s][d], pre-scaled
    #pragma unroll
    for (int cb = 0; cb < 8; ++cb) {
      int n = n0 + cb * 16 + lm;
      float bvv = bias[n];
      int hh = n >> 6, d = n & 63;
      #pragma unroll
      for (int ms = 0; ms < 2; ++ms) {
        #pragma unroll
        for (int r = 0; r < 4; ++r) {
          int m = m0 + w * 32 + ms * 16 + qd * 4 + r;
          int bidx = m >> 11, s = m & (SS - 1);
          qbuf[((long)(bidx * HH + hh) * SS + s) * HD + d] =
              f2bf((acc[cb][ms][r] + bvv) * SCALEQ);
        }
      }
    }
  } else if (z == 1) {
    // K -> ktile[bh][g][c][key][8]
    #pragma unroll
    for (int cb = 0; cb < 8; ++cb) {
      int n = n0 + cb * 16 + lm;
      float bvv = bias[n];
      int hh = n >> 6, d = n & 63;
      int c = d >> 3, e = d & 7;
      #pragma unroll
      for (int ms = 0; ms < 2; ++ms) {
        #pragma unroll
        for (int r = 0; r < 4; ++r) {
          int m = m0 + w * 32 + ms * 16 + qd * 4 + r;
          int bidx = m >> 11, s = m & (SS - 1);
          long bh = bidx * HH + hh;
          ktile[bh * KVB + (s >> 6) * 4096 + c * 512 + (s & 63) * 8 + e] =
              f2bf(acc[cb][ms][r] + bvv);
        }
      }
    }
  } else {
    // V -> vtile[bh][g][c][d][8], 4 consecutive s per 8B store
    #pragma unroll
    for (int cb = 0; cb < 8; ++cb) {
      int n = n0 + cb * 16 + lm;
      float bvv = bias[n];
      int hh = n >> 6, d = n & 63;
      #pragma unroll
      for (int ms = 0; ms < 2; ++ms) {
        int m = m0 + w * 32 + ms * 16 + qd * 4;
        int bidx = m >> 11, s = m & (SS - 1);
        long bh = bidx * HH + hh;
        unsigned short o4[4];
        #pragma unroll
        for (int r = 0; r < 4; ++r) o4[r] = f2bf(acc[cb][ms][r] + bvv);
        *(s4v*)&vtile[bh * KVB + (s >> 6) * 4096 + ((s & 63) >> 3) * 512 +
                      d * 8 + (s & 7)] = *(s4v*)o4;
      }
    }
  }
}

// ---------------------------------------------------------------------------
// Flash attention — UNCHANGED from round 8 (86 µs, passed, conflicts 0.98M).
__global__ __launch_bounds__(256, 2) void attn(
    const unsigned short* __restrict__ qb, const unsigned short* __restrict__ ktile,
    const unsigned short* __restrict__ vtile, const float* __restrict__ tableF,
    const float* __restrict__ mkg, float* __restrict__ out) {
  __shared__ __align__(16) unsigned short ks[2][8][64][8];  // [buf][d-chunk][key][8d]
  __shared__ __align__(16) unsigned short vs[2][8][64][8];  // [buf][k-chunk][d][8k]
  __shared__ __align__(16) unsigned short qr2[NREL][130];   // [dist][q_local+pad]

  const int bh = blockIdx.y, b = bh >> 4, h = bh & 15;
  const int q0 = blockIdx.x * 128;
  const int t = threadIdx.x, w = t >> 6, l = t & 63;
  const int lm = l & 15, qd = l >> 4;
  const int qw = q0 + w * 32;          // this wave's q base (32 rows)
  const int qc0 = w * 32 + lm, qc1 = qc0 + 16;  // local q cols of the 2 subtiles

  const unsigned short* kkb = ktile + (long)bh * KVB;
  const unsigned short* vvb = vtile + (long)bh * KVB;

  // stage round 0 (key-group 0) into buf 0: lane-contiguous 1KB bursts
  #pragma unroll
  for (int i = 0; i < 2; ++i) {
    int c = 2 * w + i;
    gl_lds16(kkb + c * 512 + l * 8, &ks[0][c][0][0]);
    gl_lds16(vvb + c * 512 + l * 8, &vs[0][c][0][0]);
  }

  // Q fragments for both subtiles (q = qw + lm and qw + 16 + lm), pre-scaled
  const unsigned short* qrow = qb + ((long)bh * SS + qw + lm) * HD;
  const s8v qa0 = *(const s8v*)(qrow + qd * 8);
  const s8v qa1 = *(const s8v*)(qrow + 32 + qd * 8);
  const s8v qb0 = *(const s8v*)(qrow + 16 * HD + qd * 8);
  const s8v qb1 = *(const s8v*)(qrow + 16 * HD + 32 + qd * 8);

  // Fused qrel: qr2[dist][q_local] = q_scaled . table[dist], both subtiles
  #pragma unroll
  for (int cb = 0; cb < 9; ++cb) {
    int dist = cb * 16 + lm;
    int dc = dist > NREL - 1 ? NREL - 1 : dist;
    const float* trow = tableF + dc * HD;
    f4 t0 = *(const f4*)(trow + qd * 8);
    f4 t1 = *(const f4*)(trow + qd * 8 + 4);
    f4 t2 = *(const f4*)(trow + 32 + qd * 8);
    f4 t3 = *(const f4*)(trow + 32 + qd * 8 + 4);
    unsigned int tb[8];
    tb[0] = pk2bf(t0[0], t0[1]); tb[1] = pk2bf(t0[2], t0[3]);
    tb[2] = pk2bf(t1[0], t1[1]); tb[3] = pk2bf(t1[2], t1[3]);
    tb[4] = pk2bf(t2[0], t2[1]); tb[5] = pk2bf(t2[2], t2[3]);
    tb[6] = pk2bf(t3[0], t3[1]); tb[7] = pk2bf(t3[2], t3[3]);
    s8v b0 = *(s8v*)tb, b1 = *(s8v*)(tb + 4);
    f4 c0 = MFMA_BF16(qa0, b0, (f4)0.0f, 0, 0, 0);
    c0 = MFMA_BF16(qa1, b1, c0, 0, 0, 0);
    f4 c1 = MFMA_BF16(qb0, b0, (f4)0.0f, 0, 0, 0);
    c1 = MFMA_BF16(qb1, b1, c1, 0, 0, 0);
    if (dist <= NREL - 1) {
      #pragma unroll
      for (int r = 0; r < 4; ++r) {
        qr2[dist][w * 32 + qd * 4 + r] = f2bf(c0[r]);
        qr2[dist][w * 32 + 16 + qd * 4 + r] = f2bf(c1[r]);
      }
    }
  }
  asm volatile("s_waitcnt vmcnt(0)" ::: "memory");
  __syncthreads();

  const float bLo0 = bf2f(qr2[0][qc0]), bHi0 = bf2f(qr2[128][qc0]);
  const float bLo1 = bf2f(qr2[0][qc1]), bHi1 = bf2f(qr2[128][qc1]);
  const float* mrow = mkg + b * SS;               // mask*LOG2E (L1-resident)

  float m0_ = -1e30f, l0_ = 0.0f, m1_ = -1e30f, l1_ = 0.0f;
  f4 c40[4], c41[4];
  #pragma unroll
  for (int i = 0; i < 4; ++i) { c40[i] = (f4)0.0f; c41[i] = (f4)0.0f; }

  for (int rr = 0; rr < 32; ++rr) {
    const int kk = rr << 6;
    const int buf = rr & 1;
    if (rr < 31) {
      const int nb = buf ^ 1;
      const unsigned short* kg = kkb + (rr + 1) * 4096;
      const unsigned short* vg = vvb + (rr + 1) * 4096;
      #pragma unroll
      for (int i = 0; i < 2; ++i) {
        int c = 2 * w + i;
        gl_lds16(kg + c * 512 + l * 8, &ks[nb][c][0][0]);
        gl_lds16(vg + c * 512 + l * 8, &vs[nb][c][0][0]);
      }
    }
    // QK^T for both subtiles: K fragments read once, used twice
    f4 st0[4], st1[4];
    #pragma unroll
    for (int tt = 0; tt < 4; ++tt) {
      s8v k0v = *(const s8v*)&ks[buf][qd][tt * 16 + lm][0];
      s8v k1v = *(const s8v*)&ks[buf][4 + qd][tt * 16 + lm][0];
      st0[tt] = MFMA_BF16(k0v, qa0, (f4)0.0f, 0, 0, 0);
      st0[tt] = MFMA_BF16(k1v, qa1, st0[tt], 0, 0, 0);
      st1[tt] = MFMA_BF16(k0v, qb0, (f4)0.0f, 0, 0, 0);
      st1[tt] = MFMA_BF16(k1v, qb1, st1[tt], 0, 0, 0);
    }
    float z0[16], z1[16];
    const int kw = kk - qw;  // key-band offset relative to this wave's q range
    if (kw >= 96) {          // all dist >= 65 for this wave's 32 q
      #pragma unroll
      for (int tt = 0; tt < 4; ++tt) {
        f4 mv = *(const f4*)&mrow[kk + tt * 16 + qd * 4];
        #pragma unroll
        for (int r = 0; r < 4; ++r) {
          z0[tt * 4 + r] = st0[tt][r] + bHi0 + mv[r];
          z1[tt * 4 + r] = st1[tt][r] + bHi1 + mv[r];
        }
      }
    } else if (kw <= -128) { // all dist <= -65
      #pragma unroll
      for (int tt = 0; tt < 4; ++tt) {
        f4 mv = *(const f4*)&mrow[kk + tt * 16 + qd * 4];
        #pragma unroll
        for (int r = 0; r < 4; ++r) {
          z0[tt * 4 + r] = st0[tt][r] + bLo0 + mv[r];
          z1[tt * 4 + r] = st1[tt][r] + bLo1 + mv[r];
        }
      }
    } else {                 // diagonal band (3 iters/wave): LDS qrel lookups
      const int db0 = kw - lm + 64 + qd * 4;
      #pragma unroll
      for (int tt = 0; tt < 4; ++tt) {
        f4 mv = *(const f4*)&mrow[kk + tt * 16 + qd * 4];
        #pragma unroll
        for (int r = 0; r < 4; ++r) {
          int du = db0 + tt * 16 + r;
          int d0 = du < 0 ? 0 : (du > 128 ? 128 : du);
          int d1 = du - 16; d1 = d1 < 0 ? 0 : (d1 > 128 ? 128 : d1);
          z0[tt * 4 + r] = st0[tt][r] + bf2f(qr2[d0][qc0]) + mv[r];
          z1[tt * 4 + r] = st1[tt][r] + bf2f(qr2[d1][qc1]) + mv[r];
        }
      }
    }
    // defer-max with per-group tm; cross-group shuffles only on rescale
    float tm0 = z0[0], tm1 = z1[0];
    #pragma unroll
    for (int i = 1; i < 16; ++i) {
      tm0 = fmaxf(tm0, z0[i]);
      tm1 = fmaxf(tm1, z1[i]);
    }
    if (!__all(tm0 - m0_ <= 8.0f)) {
      tm0 = fmaxf(tm0, __shfl_xor(tm0, 16));
      tm0 = fmaxf(tm0, __shfl_xor(tm0, 32));
      float mn0 = fmaxf(m0_, tm0);
      float al0 = __builtin_amdgcn_exp2f(m0_ - mn0);
      m0_ = mn0; l0_ *= al0;
      #pragma unroll
      for (int db = 0; db < 4; ++db)
        #pragma unroll
        for (int r = 0; r < 4; ++r) c40[db][r] *= al0;
    }
    if (!__all(tm1 - m1_ <= 8.0f)) {
      tm1 = fmaxf(tm1, __shfl_xor(tm1, 16));
      tm1 = fmaxf(tm1, __shfl_xor(tm1, 32));
      float mn1 = fmaxf(m1_, tm1);
      float al1 = __builtin_amdgcn_exp2f(m1_ - mn1);
      m1_ = mn1; l1_ *= al1;
      #pragma unroll
      for (int db = 0; db < 4; ++db)
        #pragma unroll
        for (int r = 0; r < 4; ++r) c41[db][r] *= al1;
    }
    float s0 = 0.0f, s1 = 0.0f;
    #pragma unroll
    for (int i = 0; i < 16; ++i) {
      z0[i] = __builtin_amdgcn_exp2f(z0[i] - m0_); s0 += z0[i];
      z1[i] = __builtin_amdgcn_exp2f(z1[i] - m1_); s1 += z1[i];
    }
    s0 += __shfl_xor(s0, 16);
    s0 += __shfl_xor(s0, 32);
    s1 += __shfl_xor(s1, 16);
    s1 += __shfl_xor(s1, 32);
    l0_ += s0; l1_ += s1;

    // PV phase A (keys 0..31): P fragments built fully in-register
    {
      s8v pa0 = mkfrag(z0[0], z0[1], z0[2], z0[3], z0[4], z0[5], z0[6], z0[7]);
      s8v pa1 = mkfrag(z1[0], z1[1], z1[2], z1[3], z1[4], z1[5], z1[6], z1[7]);
      #pragma unroll
      for (int db = 0; db < 4; ++db) {
        s8v va = *(const s8v*)&vs[buf][qd][db * 16 + lm][0];
        c40[db] = MFMA_BF16(va, pa0, c40[db], 0, 0, 0);
        c41[db] = MFMA_BF16(va, pa1, c41[db], 0, 0, 0);
      }
    }
    // PV phase B (keys 32..63)
    {
      s8v pB0 = mkfrag(z0[8], z0[9], z0[10], z0[11], z0[12], z0[13], z0[14], z0[15]);
      s8v pB1 = mkfrag(z1[8], z1[9], z1[10], z1[11], z1[12], z1[13], z1[14], z1[15]);
      #pragma unroll
      for (int db = 0; db < 4; ++db) {
        s8v vb = *(const s8v*)&vs[buf][4 + qd][db * 16 + lm][0];
        c40[db] = MFMA_BF16(vb, pB0, c40[db], 0, 0, 0);
        c41[db] = MFMA_BF16(vb, pB1, c41[db], 0, 0, 0);
      }
    }
    asm volatile("s_waitcnt vmcnt(0)" ::: "memory");
    __syncthreads();
  }

  const float inv0 = 1.0f / l0_, inv1 = 1.0f / l1_;
  float* ob0 = out + ((long)b * SS + q0 + qc0) * DD + h * HD;
  float* ob1 = out + ((long)b * SS + q0 + qc1) * DD + h * HD;
  #pragma unroll
  for (int db = 0; db < 4; ++db) {
    f4 o0, o1;
    #pragma unroll
    for (int r = 0; r < 4; ++r) {
      o0[r] = c40[db][r] * inv0;
      o1[r] = c41[db][r] * inv1;
    }
    *(f4*)(ob0 + db * 16 + qd * 4) = o0;
    *(f4*)(ob1 + db * 16 + qd * 4) = o1;
  }
}

// ---------------------------------------------------------------------------
extern "C" void kernel_launch(void* const* d_in, const int* in_sizes, int n_in,
                              void* d_out, int out_size, void* d_ws, size_t ws_size,
                              hipStream_t stream) {
  const float* query = (const float*)d_in[0];
  const float* key   = (const float*)d_in[1];
  const float* value = (const float*)d_in[2];
  const float* mask  = (const float*)d_in[3];
  const float* Wq    = (const float*)d_in[4];
  const float* bq    = (const float*)d_in[5];
  const float* Wk    = (const float*)d_in[6];
  const float* bk    = (const float*)d_in[7];
  const float* Wv    = (const float*)d_in[8];
  const float* bv    = (const float*)d_in[9];
  const float* table = (const float*)d_in[10];

  char* ws = (char*)d_ws;
  // workspace layout (bytes), span 56 MB
  unsigned short* WTt   = (unsigned short*)(ws);               // 6,291,456 (tiled)
  float*          mkg   = (float*)(ws + (7l << 20));           // 16 KB mask*LOG2E
  unsigned short* Xb    = (unsigned short*)(ws + (8l << 20));  // 25,165,824
  unsigned short* qbuf  = (unsigned short*)(ws + (32l << 20));
  unsigned short* ktile = (unsigned short*)(ws + (40l << 20));
  unsigned short* vtile = (unsigned short*)(ws + (48l << 20));

  // 1) fused conversions: inputs fp32->bf16 + mask pre-scale + weight tiling
  cvt_fused<<<dim3(2048, 4, 1), 256, 0, stream>>>(
      query, key, value, mask, Wq, Wk, Wv, Xb, mkg, WTt);

  // 2) fused QKV projections — XCD-aware block remap (XCD owns m-chunk:
  //    X read from HBM once; X-slice + WT L2-resident per XCD)
  proj_gemm<<<dim3(768, 1, 1), 256, 0, stream>>>(Xb, WTt, bq, bk, bv,
                                                 qbuf, ktile, vtile);

  // 3) flash attention (round-8 proven: permlane P-transpose, defer-max)
  attn<<<dim3(16, 32, 1), 256, 0, stream>>>(qbuf, ktile, vtile, table,
                                            mkg, (float*)d_out);
}